// Round 8
// baseline (702.764 us; speedup 1.0000x reference)
//
#include <hip/hip_runtime.h>

typedef __attribute__((ext_vector_type(8))) short frag_ab;   // 8 bf16 = 4 VGPRs
typedef __attribute__((ext_vector_type(4))) float frag_cd;   // 4 fp32 acc

__device__ __forceinline__ short f2bf(float f) {
  union { float f; unsigned u; } v; v.f = f;
  unsigned r = v.u + 0x7fffu + ((v.u >> 16) & 1u);   // RNE
  return (short)(r >> 16);
}

// ---------------------------------------------------------------------------
// wconv: fp32 weights [nmat][Keff][64] -> MFMA B-fragment-ordered bf16:
// frag (s*4+ct), lane ln, elem j = W[k=s*32+(ln>>4)*8+j][n=ct*16+(ln&15)],
// zero-padded k >= Keff. One fused launch for all 7 matrices.
// ---------------------------------------------------------------------------
__device__ __forceinline__ void wconv_body(
    const float* __restrict__ W, short* __restrict__ out,
    int Keff, int S, int nmat, int tid)
{
  int per = S * 4 * 64;
  if (tid >= nmat * per) return;
  int m = tid / per, r = tid % per;
  int s = r / 256, ct = (r >> 6) & 3, ln = r & 63;
  const float* Wm = W + (size_t)m * Keff * 64;
  __align__(16) short tmp[8];
  for (int j = 0; j < 8; ++j) {
    int k = s * 32 + (ln >> 4) * 8 + j;
    int n = ct * 16 + (ln & 15);
    tmp[j] = (k < Keff) ? f2bf(Wm[k * 64 + n]) : (short)0;
  }
  *(uint4*)&out[((size_t)m * per + (size_t)(s * 4 + ct) * 64 + ln) * 8] = *(uint4*)tmp;
}

__global__ void wconv_all(const float* __restrict__ pw,
                          const float* __restrict__ u2w,
                          const float* __restrict__ u1w,
                          short* projt, short* u2t, short* u1t)
{
  int b = blockIdx.x, t = threadIdx.x;
  if (b < 3)        wconv_body(pw,  projt, 75,  3, 1, b * 256 + t);
  else if (b < 12)  wconv_body(u2w, u2t,   80,  3, 3, (b - 3) * 256 + t);
  else              wconv_body(u1w, u1t,   128, 4, 3, (b - 12) * 256 + t);
}

// ---------------------------------------------------------------------------
// proj: hbf = bf16(x @ pw + pb).  One-time; LDS-staged A (x fp32, 75-wide).
// ---------------------------------------------------------------------------
#define AS1 104
__global__ __launch_bounds__(256, 4) void proj_kernel(
    const float* __restrict__ x, const short* __restrict__ wt,
    const float* __restrict__ bias, short* __restrict__ hbf, int N)
{
  __shared__ __align__(16) short A[128 * AS1];
  int t = threadIdx.x;
  int nb = blockIdx.x * 128;
  int ln = t & 63;
  frag_ab bf[12];
  for (int s = 0; s < 3; ++s)
    for (int ct = 0; ct < 4; ++ct)
      bf[s * 4 + ct] = *(const frag_ab*)&wt[((size_t)(s * 4 + ct) * 64 + ln) * 8];
  for (int i = 0; i < 48; ++i) {                 // 128*96/256
    int q = i * 256 + t; int el = q / 96; int c = q - el * 96;
    int rg = nb + el;
    float v = (c < 75 && rg < N) ? x[rg * 75 + c] : 0.f;
    A[el * AS1 + c] = f2bf(v);
  }
  __syncthreads();
  int wv = t >> 6;
  int lrow = ln & 15, lk = ln >> 4;
  frag_cd acc[2][4];
  for (int rt = 0; rt < 2; ++rt) for (int ct = 0; ct < 4; ++ct) {
    frag_cd z = {0.f, 0.f, 0.f, 0.f}; acc[rt][ct] = z;
  }
  for (int s = 0; s < 3; ++s) {
    frag_ab a0 = *(const frag_ab*)&A[(wv*32 + lrow) * AS1 + s*32 + lk*8];
    frag_ab a1 = *(const frag_ab*)&A[(wv*32 + 16 + lrow) * AS1 + s*32 + lk*8];
    for (int ct = 0; ct < 4; ++ct) {
      acc[0][ct] = __builtin_amdgcn_mfma_f32_16x16x32_bf16(a0, bf[s*4+ct], acc[0][ct], 0, 0, 0);
      acc[1][ct] = __builtin_amdgcn_mfma_f32_16x16x32_bf16(a1, bf[s*4+ct], acc[1][ct], 0, 0, 0);
    }
  }
  float bv[4];
  for (int ct = 0; ct < 4; ++ct) bv[ct] = bias[ct*16 + lrow];
  for (int rt = 0; rt < 2; ++rt)
    for (int ct = 0; ct < 4; ++ct)
      for (int r = 0; r < 4; ++r) {
        int row = wv*32 + rt*16 + lk*4 + r;
        int rg = nb + row;
        if (rg < N) hbf[(size_t)rg * 64 + ct*16 + lrow] = f2bf(acc[rt][ct][r] + bv[ct]);
      }
}

// ---------------------------------------------------------------------------
// Counting sort by dst. hist captures rank (atomic return); scatter is
// atomic-free and writes ONE full 64B record line per edge (no RFO):
//   q0 = {src, dst, 0, 0} | q1,q2 = attr bf16[16] | q3 = 0
// ---------------------------------------------------------------------------
__global__ __launch_bounds__(256) void hist_kernel(
    const int* __restrict__ dst, int* __restrict__ counts,
    int* __restrict__ rank, int E)
{
  int i = blockIdx.x * 256 + threadIdx.x;
  if (i < E) rank[i] = atomicAdd(&counts[dst[i]], 1);
}

#define SCAN_TILE 2048
__global__ __launch_bounds__(256) void scan_k1(
    const int* __restrict__ counts, int* __restrict__ offsets,
    int* __restrict__ bsum, int n)
{
  __shared__ int ts[256];
  int t = threadIdx.x;
  int base = blockIdx.x * SCAN_TILE + t * 8;
  int v[8]; int s = 0;
  for (int j = 0; j < 8; ++j) { v[j] = (base + j < n) ? counts[base + j] : 0; s += v[j]; }
  ts[t] = s; __syncthreads();
  for (int off = 1; off < 256; off <<= 1) {
    int x = (t >= off) ? ts[t - off] : 0;
    __syncthreads();
    ts[t] += x;
    __syncthreads();
  }
  if (t == 255) bsum[blockIdx.x] = ts[255];
  int run = (t > 0) ? ts[t - 1] : 0;
  for (int j = 0; j < 8; ++j) { if (base + j < n) offsets[base + j] = run; run += v[j]; }
}

// scan_k3 with fused block-sum prefix (nb <= 64): wave 0 shfl-scans bsum.
__global__ __launch_bounds__(256) void scan_k3(
    int* __restrict__ offsets, const int* __restrict__ bsum, int n, int nb)
{
  __shared__ int adds;
  int t = threadIdx.x;
  if (t < 64) {
    int v = (t < nb) ? bsum[t] : 0;
    int x = v;
    for (int o = 1; o < 64; o <<= 1) { int y = __shfl_up(x, o); if (t >= o) x += y; }
    int b = blockIdx.x;
    int a = __shfl(x, b - 1);                    // inclusive at b-1
    if (t == 0) adds = (b == 0) ? 0 : a;
  }
  __syncthreads();
  int add = adds;
  int base = blockIdx.x * SCAN_TILE + t;
  for (int j = 0; j < 8; ++j) { int i = base + j * 256; if (i < n) offsets[i] += add; }
}

__global__ __launch_bounds__(256) void scatter_kernel(
    const int* __restrict__ src, const int* __restrict__ dst,
    const float* __restrict__ attr, const int* __restrict__ offsets,
    const int* __restrict__ rank, uint4* __restrict__ rec, int E)
{
  int e = blockIdx.x * 256 + threadIdx.x;
  if (e < E) {
    int d = dst[e];
    int p = offsets[d] + rank[e];
    const float4* a4 = (const float4*)(attr + (size_t)e * 16);
    float4 v0 = a4[0], v1 = a4[1], v2 = a4[2], v3 = a4[3];
    __align__(16) short tmp[16];
    tmp[0]=f2bf(v0.x); tmp[1]=f2bf(v0.y); tmp[2]=f2bf(v0.z); tmp[3]=f2bf(v0.w);
    tmp[4]=f2bf(v1.x); tmp[5]=f2bf(v1.y); tmp[6]=f2bf(v1.z); tmp[7]=f2bf(v1.w);
    tmp[8]=f2bf(v2.x); tmp[9]=f2bf(v2.y); tmp[10]=f2bf(v2.z); tmp[11]=f2bf(v2.w);
    tmp[12]=f2bf(v3.x); tmp[13]=f2bf(v3.y); tmp[14]=f2bf(v3.z); tmp[15]=f2bf(v3.w);
    uint4* rp = rec + (size_t)p * 4;
    uint4 q0; q0.x = (unsigned)src[e]; q0.y = (unsigned)d; q0.z = 0u; q0.w = 0u;
    uint4 qz = {0u, 0u, 0u, 0u};
    rp[0] = q0;
    rp[1] = *(uint4*)&tmp[0];
    rp[2] = *(uint4*)&tmp[8];
    rp[3] = qz;                                  // full 64B line covered — no RFO
  }
}

// ---------------------------------------------------------------------------
// msg: A-fragments direct from global. Per row p: src/dst + attr all live in
// rec[p]'s single 64B line. LDS only for M + dstl. Segment masks via ballot;
// interior runs plain-store, boundary runs atomic. agg zeroed before launch.
// ---------------------------------------------------------------------------
#define MS 66
__global__ __launch_bounds__(256, 4) void msg_kernel(
    const short* __restrict__ hbf, const uint4* __restrict__ rec,
    const short* __restrict__ wt, const float* __restrict__ bias,
    float* __restrict__ agg, int E)
{
  __shared__ float M[128 * MS];                  // 33792 B
  __shared__ int dstl[128];
  int t = threadIdx.x;
  int eb = blockIdx.x * 128;
  int ln = t & 63;
  int wv = t >> 6;
  int lrow = ln & 15, lk = ln >> 4;

  if (t < 128) {
    int p = eb + t;
    dstl[t] = (p < E) ? ((const int*)(rec + (size_t)p * 4))[1] : -1;
  }

  int p0 = eb + wv*32 + lrow;  if (p0 > E - 1) p0 = E - 1;
  int p1 = p0 + 16;            if (p1 > E - 1) p1 = E - 1;
  int s0 = ((const int*)(rec + (size_t)p0 * 4))[0];
  int s1 = ((const int*)(rec + (size_t)p1 * 4))[0];

  frag_ab a[3][2];
  a[0][0] = *(const frag_ab*)&hbf[(size_t)s0 * 64 + lk*8];
  a[0][1] = *(const frag_ab*)&hbf[(size_t)s1 * 64 + lk*8];
  a[1][0] = *(const frag_ab*)&hbf[(size_t)s0 * 64 + 32 + lk*8];
  a[1][1] = *(const frag_ab*)&hbf[(size_t)s1 * 64 + 32 + lk*8];
  frag_ab z8 = {0,0,0,0,0,0,0,0};
  a[2][0] = (lk < 2) ? *(const frag_ab*)((const short*)(rec + (size_t)p0 * 4) + 8 + lk*8) : z8;
  a[2][1] = (lk < 2) ? *(const frag_ab*)((const short*)(rec + (size_t)p1 * 4) + 8 + lk*8) : z8;

  frag_cd acc[2][4];
  for (int rt = 0; rt < 2; ++rt) for (int ct = 0; ct < 4; ++ct) {
    frag_cd z = {0.f, 0.f, 0.f, 0.f}; acc[rt][ct] = z;
  }
  for (int s = 0; s < 3; ++s)
    for (int ct = 0; ct < 4; ++ct) {
      frag_ab b = *(const frag_ab*)&wt[((size_t)(s * 4 + ct) * 64 + ln) * 8];
      acc[0][ct] = __builtin_amdgcn_mfma_f32_16x16x32_bf16(a[s][0], b, acc[0][ct], 0, 0, 0);
      acc[1][ct] = __builtin_amdgcn_mfma_f32_16x16x32_bf16(a[s][1], b, acc[1][ct], 0, 0, 0);
    }
  float bv[4];
  for (int ct = 0; ct < 4; ++ct) bv[ct] = bias[ct*16 + lrow];

  for (int rt = 0; rt < 2; ++rt)
    for (int ct = 0; ct < 4; ++ct)
      for (int r = 0; r < 4; ++r) {
        int row = wv*32 + rt*16 + lk*4 + r;
        float m = acc[rt][ct][r] + bv[ct];
        m = m > 0.f ? m : 0.1f * m;              // LeakyReLU(0.1)
        M[row * MS + ct*16 + lrow] = m;
      }
  __syncthreads();

  // segmented reduction: wave wv owns rows [wv*32, wv*32+32), lane ln owns col ln.
  {
    int lo = wv * 32;
    bool end = false;
    if (ln < 32) {
      int di = dstl[lo + ln];
      end = (ln == 31) || (di != dstl[lo + ln + 1]);
    }
    unsigned long long bm = __ballot(end);
    unsigned em = (unsigned)bm;
    unsigned cm = em & ~(em & (0u - em)) & 0x7fffffffu;

    float s = 0.f;
#pragma unroll
    for (int i = 0; i < 32; ++i) {
      s += M[(lo + i) * MS + ln];
      if ((em >> i) & 1u) {
        int d = __builtin_amdgcn_readfirstlane(dstl[lo + i]);
        if (d >= 0) {
          float* dest = &agg[(size_t)d * 64 + ln];
          if ((cm >> i) & 1u) *dest = s;
          else unsafeAtomicAdd(dest, s);
        }
        s = 0.f;
      }
    }
  }
}

// ---------------------------------------------------------------------------
// upd: no LDS. A-frags direct from global: s<2 -> hbf, s>=2 -> agg (fp32->bf16
// in-reg) with fused re-zeroing. In-place hbf safe (wave-private 32-row window).
// fp32 output written only on last layer.
// ---------------------------------------------------------------------------
__global__ __launch_bounds__(256, 4) void upd_kernel(
    const short* __restrict__ hbf, float* __restrict__ agg,
    const short* __restrict__ wt, const float* __restrict__ bias,
    float* __restrict__ hout, short* __restrict__ hbfo, int N, int last)
{
  int t = threadIdx.x;
  int nb = blockIdx.x * 128;
  int ln = t & 63;
  int wv = t >> 6;
  int lrow = ln & 15, lk = ln >> 4;
  int r0 = nb + wv*32 + lrow;
  int r1 = r0 + 16;

  frag_ab z8 = {0,0,0,0,0,0,0,0};
  frag_ab a[4][2];
  a[0][0] = (r0 < N) ? *(const frag_ab*)&hbf[(size_t)r0 * 64 + lk*8]      : z8;
  a[0][1] = (r1 < N) ? *(const frag_ab*)&hbf[(size_t)r1 * 64 + lk*8]      : z8;
  a[1][0] = (r0 < N) ? *(const frag_ab*)&hbf[(size_t)r0 * 64 + 32 + lk*8] : z8;
  a[1][1] = (r1 < N) ? *(const frag_ab*)&hbf[(size_t)r1 * 64 + 32 + lk*8] : z8;
  for (int si = 0; si < 2; ++si) {
    int cb = si * 32 + lk * 8;                   // agg col base
    for (int rt = 0; rt < 2; ++rt) {
      int rg = rt ? r1 : r0;
      frag_ab af = z8;
      if (rg < N) {
        float* ap = &agg[(size_t)rg * 64 + cb];
        float4 v0 = *(const float4*)ap;
        float4 v1 = *(const float4*)(ap + 4);
        af[0]=f2bf(v0.x); af[1]=f2bf(v0.y); af[2]=f2bf(v0.z); af[3]=f2bf(v0.w);
        af[4]=f2bf(v1.x); af[5]=f2bf(v1.y); af[6]=f2bf(v1.z); af[7]=f2bf(v1.w);
        if (!last) {
          float4 z = make_float4(0.f, 0.f, 0.f, 0.f);
          *(float4*)ap = z; *(float4*)(ap + 4) = z;
        }
      }
      a[2 + si][rt] = af;
    }
  }

  frag_cd acc[2][4];
  for (int rt = 0; rt < 2; ++rt) for (int ct = 0; ct < 4; ++ct) {
    frag_cd z = {0.f, 0.f, 0.f, 0.f}; acc[rt][ct] = z;
  }
  for (int s = 0; s < 4; ++s)
    for (int ct = 0; ct < 4; ++ct) {
      frag_ab b = *(const frag_ab*)&wt[((size_t)(s * 4 + ct) * 64 + ln) * 8];
      acc[0][ct] = __builtin_amdgcn_mfma_f32_16x16x32_bf16(a[s][0], b, acc[0][ct], 0, 0, 0);
      acc[1][ct] = __builtin_amdgcn_mfma_f32_16x16x32_bf16(a[s][1], b, acc[1][ct], 0, 0, 0);
    }
  float bv[4];
  for (int ct = 0; ct < 4; ++ct) bv[ct] = bias[ct*16 + lrow];
  for (int rt = 0; rt < 2; ++rt)
    for (int ct = 0; ct < 4; ++ct)
      for (int r = 0; r < 4; ++r) {
        int row = wv*32 + rt*16 + lk*4 + r;
        int rg = nb + row;
        if (rg < N) {
          float v = acc[rt][ct][r] + bv[ct];
          if (last) hout[(size_t)rg * 64 + ct*16 + lrow] = v;
          hbfo[(size_t)rg * 64 + ct*16 + lrow] = f2bf(v);
        }
      }
}

extern "C" void kernel_launch(void* const* d_in, const int* in_sizes, int n_in,
                              void* d_out, int out_size, void* d_ws, size_t ws_size,
                              hipStream_t stream) {
  const float* x    = (const float*)d_in[0];
  const int*   ei   = (const int*)d_in[1];
  const float* attr = (const float*)d_in[2];
  const float* pw   = (const float*)d_in[3];
  const float* pb   = (const float*)d_in[4];
  const float* u2w  = (const float*)d_in[5];
  const float* u2b  = (const float*)d_in[6];
  const float* u1w  = (const float*)d_in[7];
  const float* u1b  = (const float*)d_in[8];

  const int N = in_sizes[0] / 75;
  const int E = in_sizes[1] / 2;
  const int* src = ei;
  const int* dst = ei + E;

  float* hout = (float*)d_out;
  char*  ws   = (char*)d_ws;
  size_t nh   = (size_t)N * 64;
  size_t off  = 0;
  short* hbf   = (short*)(ws + off); off += nh * 2;              //  12.8 MB
  float* agg   = (float*)(ws + off); off += nh * 4;              //  25.6 MB
  uint4* rec   = (uint4*)(ws + off); off += (size_t)E * 64;      // 102.4 MB
  short* projt = (short*)(ws + off); off += 3 * 4 * 64 * 8 * 2;
  short* u2t   = (short*)(ws + off); off += (size_t)3 * 3 * 4 * 64 * 8 * 2;
  short* u1t   = (short*)(ws + off); off += (size_t)3 * 4 * 4 * 64 * 8 * 2;
  // sort scratch overlays agg (dead until msg):
  int* counts  = (int*)agg;
  int* offsets = counts + N;
  int* bsum    = offsets + N;
  int* rank    = bsum + 64;

  const int NB = (N + 127) / 128;
  const int EB = (E + 127) / 128;
  const int GE = (E + 255) / 256;
  const int NS = (N + SCAN_TILE - 1) / SCAN_TILE;

  // one-time preprocessing
  wconv_all<<<24, 256, 0, stream>>>(pw, u2w, u1w, projt, u2t, u1t);
  proj_kernel<<<NB, 256, 0, stream>>>(x, projt, pb, hbf, N);
  hipMemsetAsync(counts, 0, (size_t)N * 4, stream);
  hist_kernel<<<GE, 256, 0, stream>>>(dst, counts, rank, E);
  scan_k1<<<NS, 256, 0, stream>>>(counts, offsets, bsum, N);
  scan_k3<<<NS, 256, 0, stream>>>(offsets, bsum, N, NS);
  scatter_kernel<<<GE, 256, 0, stream>>>(src, dst, attr, offsets, rank, rec, E);

  hipMemsetAsync(agg, 0, nh * 4, stream);       // layer-0 base; upd re-zeros after
  for (int l = 0; l < 3; ++l) {
    msg_kernel<<<EB, 256, 0, stream>>>(hbf, rec,
                                       u2t + (size_t)l * 6144, u2b + l * 64,
                                       agg, E);
    upd_kernel<<<NB, 256, 0, stream>>>(hbf, agg,
                                       u1t + (size_t)l * 8192, u1b + l * 64,
                                       hout, hbf, N, l == 2);
  }
}

// Round 9
// 644.713 us; speedup vs baseline: 1.0900x; 1.0900x over previous
//
#include <hip/hip_runtime.h>

typedef __attribute__((ext_vector_type(8))) short frag_ab;   // 8 bf16 = 4 VGPRs
typedef __attribute__((ext_vector_type(4))) float frag_cd;   // 4 fp32 acc

__device__ __forceinline__ short f2bf(float f) {
  union { float f; unsigned u; } v; v.f = f;
  unsigned r = v.u + 0x7fffu + ((v.u >> 16) & 1u);   // RNE
  return (short)(r >> 16);
}
__device__ __forceinline__ float bf2f(short s) {
  union { unsigned u; float f; } v; v.u = ((unsigned)(unsigned short)s) << 16;
  return v.f;
}

// ---------------------------------------------------------------------------
// wconv: fp32 weights [nmat][Keff][64] -> MFMA B-fragment-ordered bf16:
// frag (s*4+ct), lane ln, elem j = W[k=s*32+(ln>>4)*8+j][n=ct*16+(ln&15)],
// zero-padded k >= Keff. One fused launch for all 7 matrices.
// ---------------------------------------------------------------------------
__device__ __forceinline__ void wconv_body(
    const float* __restrict__ W, short* __restrict__ out,
    int Keff, int S, int nmat, int tid)
{
  int per = S * 4 * 64;
  if (tid >= nmat * per) return;
  int m = tid / per, r = tid % per;
  int s = r / 256, ct = (r >> 6) & 3, ln = r & 63;
  const float* Wm = W + (size_t)m * Keff * 64;
  __align__(16) short tmp[8];
  for (int j = 0; j < 8; ++j) {
    int k = s * 32 + (ln >> 4) * 8 + j;
    int n = ct * 16 + (ln & 15);
    tmp[j] = (k < Keff) ? f2bf(Wm[k * 64 + n]) : (short)0;
  }
  *(uint4*)&out[((size_t)m * per + (size_t)(s * 4 + ct) * 64 + ln) * 8] = *(uint4*)tmp;
}

__global__ void wconv_all(const float* __restrict__ pw,
                          const float* __restrict__ u2w,
                          const float* __restrict__ u1w,
                          short* projt, short* u2t, short* u1t)
{
  int b = blockIdx.x, t = threadIdx.x;
  if (b < 3)        wconv_body(pw,  projt, 75,  3, 1, b * 256 + t);
  else if (b < 12)  wconv_body(u2w, u2t,   80,  3, 3, (b - 3) * 256 + t);
  else              wconv_body(u1w, u1t,   128, 4, 3, (b - 12) * 256 + t);
}

// ---------------------------------------------------------------------------
// proj: hbf = bf16(x @ pw + pb).  One-time; LDS-staged A (x fp32, 75-wide).
// ---------------------------------------------------------------------------
#define AS1 104
__global__ __launch_bounds__(256, 4) void proj_kernel(
    const float* __restrict__ x, const short* __restrict__ wt,
    const float* __restrict__ bias, short* __restrict__ hbf, int N)
{
  __shared__ __align__(16) short A[128 * AS1];
  int t = threadIdx.x;
  int nb = blockIdx.x * 128;
  int ln = t & 63;
  frag_ab bf[12];
  for (int s = 0; s < 3; ++s)
    for (int ct = 0; ct < 4; ++ct)
      bf[s * 4 + ct] = *(const frag_ab*)&wt[((size_t)(s * 4 + ct) * 64 + ln) * 8];
  for (int i = 0; i < 48; ++i) {                 // 128*96/256
    int q = i * 256 + t; int el = q / 96; int c = q - el * 96;
    int rg = nb + el;
    float v = (c < 75 && rg < N) ? x[rg * 75 + c] : 0.f;
    A[el * AS1 + c] = f2bf(v);
  }
  __syncthreads();
  int wv = t >> 6;
  int lrow = ln & 15, lk = ln >> 4;
  frag_cd acc[2][4];
  for (int rt = 0; rt < 2; ++rt) for (int ct = 0; ct < 4; ++ct) {
    frag_cd z = {0.f, 0.f, 0.f, 0.f}; acc[rt][ct] = z;
  }
  for (int s = 0; s < 3; ++s) {
    frag_ab a0 = *(const frag_ab*)&A[(wv*32 + lrow) * AS1 + s*32 + lk*8];
    frag_ab a1 = *(const frag_ab*)&A[(wv*32 + 16 + lrow) * AS1 + s*32 + lk*8];
    for (int ct = 0; ct < 4; ++ct) {
      acc[0][ct] = __builtin_amdgcn_mfma_f32_16x16x32_bf16(a0, bf[s*4+ct], acc[0][ct], 0, 0, 0);
      acc[1][ct] = __builtin_amdgcn_mfma_f32_16x16x32_bf16(a1, bf[s*4+ct], acc[1][ct], 0, 0, 0);
    }
  }
  float bv[4];
  for (int ct = 0; ct < 4; ++ct) bv[ct] = bias[ct*16 + lrow];
  for (int rt = 0; rt < 2; ++rt)
    for (int ct = 0; ct < 4; ++ct)
      for (int r = 0; r < 4; ++r) {
        int row = wv*32 + rt*16 + lk*4 + r;
        int rg = nb + row;
        if (rg < N) hbf[(size_t)rg * 64 + ct*16 + lrow] = f2bf(acc[rt][ct][r] + bv[ct]);
      }
}

// ---------------------------------------------------------------------------
// Counting sort by dst. hist captures rank (atomic return); scatter is
// atomic-free and writes ONE full 64B record line per edge (no RFO):
//   q0 = {src, dst, 0, 0} | q1,q2 = attr bf16[16] | q3 = 0
// ---------------------------------------------------------------------------
__global__ __launch_bounds__(256) void hist_kernel(
    const int* __restrict__ dst, int* __restrict__ counts,
    int* __restrict__ rank, int E)
{
  int i = blockIdx.x * 256 + threadIdx.x;
  if (i < E) rank[i] = atomicAdd(&counts[dst[i]], 1);
}

#define SCAN_TILE 2048
__global__ __launch_bounds__(256) void scan_k1(
    const int* __restrict__ counts, int* __restrict__ offsets,
    int* __restrict__ bsum, int n)
{
  __shared__ int ts[256];
  int t = threadIdx.x;
  int base = blockIdx.x * SCAN_TILE + t * 8;
  int v[8]; int s = 0;
  for (int j = 0; j < 8; ++j) { v[j] = (base + j < n) ? counts[base + j] : 0; s += v[j]; }
  ts[t] = s; __syncthreads();
  for (int off = 1; off < 256; off <<= 1) {
    int x = (t >= off) ? ts[t - off] : 0;
    __syncthreads();
    ts[t] += x;
    __syncthreads();
  }
  if (t == 255) bsum[blockIdx.x] = ts[255];
  int run = (t > 0) ? ts[t - 1] : 0;
  for (int j = 0; j < 8; ++j) { if (base + j < n) offsets[base + j] = run; run += v[j]; }
}

// scan_k3 with fused block-sum prefix (nb <= 64): wave 0 shfl-scans bsum.
__global__ __launch_bounds__(256) void scan_k3(
    int* __restrict__ offsets, const int* __restrict__ bsum, int n, int nb)
{
  __shared__ int adds;
  int t = threadIdx.x;
  if (t < 64) {
    int v = (t < nb) ? bsum[t] : 0;
    int x = v;
    for (int o = 1; o < 64; o <<= 1) { int y = __shfl_up(x, o); if (t >= o) x += y; }
    int b = blockIdx.x;
    int a = __shfl(x, b - 1);                    // inclusive at b-1
    if (t == 0) adds = (b == 0) ? 0 : a;
  }
  __syncthreads();
  int add = adds;
  int base = blockIdx.x * SCAN_TILE + t;
  for (int j = 0; j < 8; ++j) { int i = base + j * 256; if (i < n) offsets[i] += add; }
}

__global__ __launch_bounds__(256) void scatter_kernel(
    const int* __restrict__ src, const int* __restrict__ dst,
    const float* __restrict__ attr, const int* __restrict__ offsets,
    const int* __restrict__ rank, uint4* __restrict__ rec, int E)
{
  int e = blockIdx.x * 256 + threadIdx.x;
  if (e < E) {
    int d = dst[e];
    int p = offsets[d] + rank[e];
    const float4* a4 = (const float4*)(attr + (size_t)e * 16);
    float4 v0 = a4[0], v1 = a4[1], v2 = a4[2], v3 = a4[3];
    __align__(16) short tmp[16];
    tmp[0]=f2bf(v0.x); tmp[1]=f2bf(v0.y); tmp[2]=f2bf(v0.z); tmp[3]=f2bf(v0.w);
    tmp[4]=f2bf(v1.x); tmp[5]=f2bf(v1.y); tmp[6]=f2bf(v1.z); tmp[7]=f2bf(v1.w);
    tmp[8]=f2bf(v2.x); tmp[9]=f2bf(v2.y); tmp[10]=f2bf(v2.z); tmp[11]=f2bf(v2.w);
    tmp[12]=f2bf(v3.x); tmp[13]=f2bf(v3.y); tmp[14]=f2bf(v3.z); tmp[15]=f2bf(v3.w);
    uint4* rp = rec + (size_t)p * 4;
    uint4 q0; q0.x = (unsigned)src[e]; q0.y = (unsigned)d; q0.z = 0u; q0.w = 0u;
    uint4 qz = {0u, 0u, 0u, 0u};
    rp[0] = q0;
    rp[1] = *(uint4*)&tmp[0];
    rp[2] = *(uint4*)&tmp[8];
    rp[3] = qz;                                  // full 64B line covered — no RFO
  }
}

// ---------------------------------------------------------------------------
// msg v5: fully wave-independent — NO __syncthreads. Each wave owns 32 sorted
// edges: direct-gather A-frags, 12 MFMAs, bf16 M round-trip through its own
// LDS rows (wave-local lgkmcnt wait), dst run structure via shfl+ballot,
// interior runs plain-store / boundary runs atomic into agg.
// ---------------------------------------------------------------------------
#define MS 66
__global__ __launch_bounds__(256, 6) void msg_kernel(
    const short* __restrict__ hbf, const uint4* __restrict__ rec,
    const short* __restrict__ wt, const float* __restrict__ bias,
    float* __restrict__ agg, int E)
{
  __shared__ short M2[128 * MS];                 // bf16 M, 16896 B
  int t = threadIdx.x;
  int eb = blockIdx.x * 128;
  int ln = t & 63;
  int wv = t >> 6;
  int lrow = ln & 15, lk = ln >> 4;
  int lo = wv * 32;

  int g0 = eb + lo + lrow;                       // this lane's two edge rows
  int g1 = g0 + 16;
  int p0 = g0 > E - 1 ? E - 1 : g0;
  int p1 = g1 > E - 1 ? E - 1 : g1;
  int2 sd0 = *(const int2*)(rec + (size_t)p0 * 4);
  int2 sd1 = *(const int2*)(rec + (size_t)p1 * 4);
  int d0 = (g0 < E) ? sd0.y : -1;
  int d1 = (g1 < E) ? sd1.y : -1;

  frag_ab a[3][2];
  a[0][0] = *(const frag_ab*)&hbf[(size_t)sd0.x * 64 + lk*8];
  a[0][1] = *(const frag_ab*)&hbf[(size_t)sd1.x * 64 + lk*8];
  a[1][0] = *(const frag_ab*)&hbf[(size_t)sd0.x * 64 + 32 + lk*8];
  a[1][1] = *(const frag_ab*)&hbf[(size_t)sd1.x * 64 + 32 + lk*8];
  frag_ab z8 = {0,0,0,0,0,0,0,0};
  a[2][0] = (lk < 2) ? *(const frag_ab*)((const short*)(rec + (size_t)p0 * 4) + 8 + lk*8) : z8;
  a[2][1] = (lk < 2) ? *(const frag_ab*)((const short*)(rec + (size_t)p1 * 4) + 8 + lk*8) : z8;

  frag_cd acc[2][4];
  for (int rt = 0; rt < 2; ++rt) for (int ct = 0; ct < 4; ++ct) {
    frag_cd z = {0.f, 0.f, 0.f, 0.f}; acc[rt][ct] = z;
  }
  for (int s = 0; s < 3; ++s)
    for (int ct = 0; ct < 4; ++ct) {
      frag_ab b = *(const frag_ab*)&wt[((size_t)(s * 4 + ct) * 64 + ln) * 8];
      acc[0][ct] = __builtin_amdgcn_mfma_f32_16x16x32_bf16(a[s][0], b, acc[0][ct], 0, 0, 0);
      acc[1][ct] = __builtin_amdgcn_mfma_f32_16x16x32_bf16(a[s][1], b, acc[1][ct], 0, 0, 0);
    }
  float bv[4];
  for (int ct = 0; ct < 4; ++ct) bv[ct] = bias[ct*16 + lrow];

  // write this wave's 32 M rows (bf16, bias + LeakyReLU applied)
  for (int rt = 0; rt < 2; ++rt)
    for (int ct = 0; ct < 4; ++ct)
      for (int r = 0; r < 4; ++r) {
        int row = lo + rt*16 + lk*4 + r;
        float m = acc[rt][ct][r] + bv[ct];
        m = m > 0.f ? m : 0.1f * m;              // LeakyReLU(0.1)
        M2[row * MS + ct*16 + lrow] = f2bf(m);
      }
  __asm__ __volatile__("s_waitcnt lgkmcnt(0)" ::: "memory");  // wave-local

  // run structure: lanes 0..31 hold dst of rows lo+0..lo+31
  int dl = (ln < 16) ? d0 : d1;
  int dnext = __shfl_down(dl, 1);
  bool end = (ln < 32) && ((ln == 31) || (dl != dnext));
  unsigned em = (unsigned)__ballot(end);
  unsigned cm = em & ~(em & (0u - em)) & 0x7fffffffu;

  float s = 0.f;
#pragma unroll
  for (int i = 0; i < 32; ++i) {
    s += bf2f(M2[(lo + i) * MS + ln]);
    if ((em >> i) & 1u) {
      int di = (i < 16) ? __shfl(d0, i) : __shfl(d1, i - 16);
      if (di >= 0) {
        float* dest = &agg[(size_t)di * 64 + ln];
        if ((cm >> i) & 1u) *dest = s;
        else unsafeAtomicAdd(dest, s);
      }
      s = 0.f;
    }
  }
}

// ---------------------------------------------------------------------------
// upd: no LDS, 64 rows/block (1 row-tile/wave) for a 2x bigger grid. A-frags
// direct from global: s<2 -> hbf, s>=2 -> agg (fp32->bf16 in-reg) with fused
// re-zeroing. In-place hbf safe (wave-private 16-row window).
// ---------------------------------------------------------------------------
__global__ __launch_bounds__(256, 4) void upd_kernel(
    const short* __restrict__ hbf, float* __restrict__ agg,
    const short* __restrict__ wt, const float* __restrict__ bias,
    float* __restrict__ hout, short* __restrict__ hbfo, int N, int last)
{
  int t = threadIdx.x;
  int nb = blockIdx.x * 64;
  int ln = t & 63;
  int wv = t >> 6;
  int lrow = ln & 15, lk = ln >> 4;
  int r0 = nb + wv*16 + lrow;

  frag_ab z8 = {0,0,0,0,0,0,0,0};
  frag_ab a[4];
  a[0] = (r0 < N) ? *(const frag_ab*)&hbf[(size_t)r0 * 64 + lk*8]      : z8;
  a[1] = (r0 < N) ? *(const frag_ab*)&hbf[(size_t)r0 * 64 + 32 + lk*8] : z8;
  for (int si = 0; si < 2; ++si) {
    int cb = si * 32 + lk * 8;                   // agg col octet
    frag_ab af = z8;
    if (r0 < N) {
      float* ap = &agg[(size_t)r0 * 64 + cb];
      float4 v0 = *(const float4*)ap;
      float4 v1 = *(const float4*)(ap + 4);
      af[0]=f2bf(v0.x); af[1]=f2bf(v0.y); af[2]=f2bf(v0.z); af[3]=f2bf(v0.w);
      af[4]=f2bf(v1.x); af[5]=f2bf(v1.y); af[6]=f2bf(v1.z); af[7]=f2bf(v1.w);
      if (!last) {
        float4 z = make_float4(0.f, 0.f, 0.f, 0.f);
        *(float4*)ap = z; *(float4*)(ap + 4) = z;
      }
    }
    a[2 + si] = af;
  }

  frag_cd acc[4];
  for (int ct = 0; ct < 4; ++ct) {
    frag_cd z = {0.f, 0.f, 0.f, 0.f}; acc[ct] = z;
  }
  for (int s = 0; s < 4; ++s)
    for (int ct = 0; ct < 4; ++ct) {
      frag_ab b = *(const frag_ab*)&wt[((size_t)(s * 4 + ct) * 64 + ln) * 8];
      acc[ct] = __builtin_amdgcn_mfma_f32_16x16x32_bf16(a[s], b, acc[ct], 0, 0, 0);
    }
  float bv[4];
  for (int ct = 0; ct < 4; ++ct) bv[ct] = bias[ct*16 + lrow];
  for (int ct = 0; ct < 4; ++ct)
    for (int r = 0; r < 4; ++r) {
      int rg = nb + wv*16 + lk*4 + r;
      if (rg < N) {
        float v = acc[ct][r] + bv[ct];
        if (last) hout[(size_t)rg * 64 + ct*16 + lrow] = v;
        hbfo[(size_t)rg * 64 + ct*16 + lrow] = f2bf(v);
      }
    }
}

extern "C" void kernel_launch(void* const* d_in, const int* in_sizes, int n_in,
                              void* d_out, int out_size, void* d_ws, size_t ws_size,
                              hipStream_t stream) {
  const float* x    = (const float*)d_in[0];
  const int*   ei   = (const int*)d_in[1];
  const float* attr = (const float*)d_in[2];
  const float* pw   = (const float*)d_in[3];
  const float* pb   = (const float*)d_in[4];
  const float* u2w  = (const float*)d_in[5];
  const float* u2b  = (const float*)d_in[6];
  const float* u1w  = (const float*)d_in[7];
  const float* u1b  = (const float*)d_in[8];

  const int N = in_sizes[0] / 75;
  const int E = in_sizes[1] / 2;
  const int* src = ei;
  const int* dst = ei + E;

  float* hout = (float*)d_out;
  char*  ws   = (char*)d_ws;
  size_t nh   = (size_t)N * 64;
  size_t off  = 0;
  short* hbf   = (short*)(ws + off); off += nh * 2;              //  12.8 MB
  float* agg   = (float*)(ws + off); off += nh * 4;              //  25.6 MB
  uint4* rec   = (uint4*)(ws + off); off += (size_t)E * 64;      // 102.4 MB
  short* projt = (short*)(ws + off); off += 3 * 4 * 64 * 8 * 2;
  short* u2t   = (short*)(ws + off); off += (size_t)3 * 3 * 4 * 64 * 8 * 2;
  short* u1t   = (short*)(ws + off); off += (size_t)3 * 4 * 4 * 64 * 8 * 2;
  // sort scratch overlays agg (dead until msg):
  int* counts  = (int*)agg;
  int* offsets = counts + N;
  int* bsum    = offsets + N;
  int* rank    = bsum + 64;

  const int NB = (N + 127) / 128;
  const int NB2 = (N + 63) / 64;
  const int EB = (E + 127) / 128;
  const int GE = (E + 255) / 256;
  const int NS = (N + SCAN_TILE - 1) / SCAN_TILE;

  // one-time preprocessing
  wconv_all<<<24, 256, 0, stream>>>(pw, u2w, u1w, projt, u2t, u1t);
  proj_kernel<<<NB, 256, 0, stream>>>(x, projt, pb, hbf, N);
  hipMemsetAsync(counts, 0, (size_t)N * 4, stream);
  hist_kernel<<<GE, 256, 0, stream>>>(dst, counts, rank, E);
  scan_k1<<<NS, 256, 0, stream>>>(counts, offsets, bsum, N);
  scan_k3<<<NS, 256, 0, stream>>>(offsets, bsum, N, NS);
  scatter_kernel<<<GE, 256, 0, stream>>>(src, dst, attr, offsets, rank, rec, E);

  hipMemsetAsync(agg, 0, nh * 4, stream);       // layer-0 base; upd re-zeros after
  for (int l = 0; l < 3; ++l) {
    msg_kernel<<<EB, 256, 0, stream>>>(hbf, rec,
                                       u2t + (size_t)l * 6144, u2b + l * 64,
                                       agg, E);
    upd_kernel<<<NB2, 256, 0, stream>>>(hbf, agg,
                                        u1t + (size_t)l * 8192, u1b + l * 64,
                                        hout, hbf, N, l == 2);
  }
}